// Round 9
// baseline (370.181 us; speedup 1.0000x reference)
//
#include <hip/hip_runtime.h>
#include <hip/hip_bf16.h>
#include <math.h>

#define R_CNT   20000
#define L_CNT   30
#define D_CNT   200
#define A_CNT   32
#define B_CNT   4096
#define NNZ_CNT 65536
#define AVG_RATING 3.8f

#define KA_GRID 1536     // persistent attn blocks: 6/CU (LDS 26.8KB)

// ---- d_out layout (floats) ----
#define OUT_OBJ  0
#define OUT_RL   1
#define OUT_AB   (1 + B_CNT)               // 4097
#define OUT_PRED (OUT_AB + 2*R_CNT)        // 44097
#define OUT_UA   (OUT_PRED + B_CNT)        // 48193
#define OUT_IA   (OUT_UA + B_CNT*A_CNT)    // 179265

// ---- ws layout (bytes) ----
#define WS_DBL    0         // double[4] (unused slots reserved)
#define WS_MODE   32        // int (1 => indices are int64 in memory)
#define WS_FMLIN  64        // float[4096]
#define WS_PT     16448     // float[R*32]
#define WS_V      2576448   // float[R*200]
#define WS_JPART  18627648  // double[KA_GRID]
#define WS_SPART  18667648  // double[512]
#define WS_UPART  18671744  // float[32]

// Raw barrier + LDS drain (keeps VMEM prefetch in flight)
#define BAR_LDS() do { asm volatile("s_waitcnt lgkmcnt(0)" ::: "memory"); \
                       __builtin_amdgcn_s_barrier(); \
                       __builtin_amdgcn_sched_barrier(0); } while (0)
// Full drain: staged LDS data + all stores landed (required by single-buffer)
#define BAR_FULL() do { asm volatile("s_waitcnt vmcnt(0) lgkmcnt(0)" ::: "memory"); \
                        __builtin_amdgcn_s_barrier(); \
                        __builtin_amdgcn_sched_barrier(0); } while (0)

// Block-wide reduction of 4 channels across 256 threads (4 waves of 64).
__device__ __forceinline__ float4 blk_reduce4(float4 v, float4* scratch) {
    __syncthreads();
    #pragma unroll
    for (int o = 32; o >= 1; o >>= 1) {
        v.x += __shfl_xor(v.x, o);
        v.y += __shfl_xor(v.y, o);
        v.z += __shfl_xor(v.z, o);
        v.w += __shfl_xor(v.w, o);
    }
    int w = threadIdx.x >> 6;
    if ((threadIdx.x & 63) == 0) scratch[w] = v;
    __syncthreads();
    float4 t0 = scratch[0], t1 = scratch[1], t2 = scratch[2], t3 = scratch[3];
    return make_float4(t0.x + t1.x + t2.x + t3.x,
                       t0.y + t1.y + t2.y + t3.y,
                       t0.z + t1.z + t2.z + t3.z,
                       t0.w + t1.w + t2.w + t3.w);
}

// ---- K_pre: role-split fusion of {vgemm | uloss | init} ----
// blocks [0,313): V = y_s @ M_w (64 rows each)
// blocks [313,345): uloss G-row per block
// blocks [345,473): zero UA/IA; block 345 inits dbl/mode
__global__ __launch_bounds__(256) void k_pre(const float* __restrict__ y_s,
                                             const float* __restrict__ M_w,
                                             const float* __restrict__ T_w,
                                             const int* __restrict__ u_idx,
                                             float* __restrict__ V,
                                             float* __restrict__ upart,
                                             float* __restrict__ out,
                                             double* __restrict__ dbl,
                                             int* __restrict__ mode) {
    __shared__ __align__(16) float sh[8224];
    const int tid = threadIdx.x;
    const int bid = blockIdx.x;

    if (bid < 313) {
        // ---- vgemm: 64 rows x 200 cols, 8x8 register tile ----
        float* Msh = sh;             // [25][260]
        float* Ysh = sh + 6500;      // [25][68]
        int r0 = bid * 64;
        int dg = tid & 31, rg = tid >> 5;
        float acc[8][8];
        #pragma unroll
        for (int i = 0; i < 8; i++)
            #pragma unroll
            for (int j = 0; j < 8; j++) acc[i][j] = 0.f;
        for (int e0 = 0; e0 < D_CNT; e0 += 25) {
            __syncthreads();
            for (int idx = tid; idx < 25 * 256; idx += 256) {
                int ee = idx >> 8, d = idx & 255;
                Msh[ee * 260 + d] = (d < D_CNT) ? M_w[(e0 + ee) * D_CNT + d] : 0.f;
            }
            for (int idx = tid; idx < 25 * 64; idx += 256) {
                int rr = idx / 25, ee = idx - rr * 25;
                int row = r0 + rr;
                Ysh[ee * 68 + rr] = (row < R_CNT) ? y_s[row * D_CNT + e0 + ee] : 0.f;
            }
            __syncthreads();
            for (int ee = 0; ee < 25; ee++) {
                const float4 ya = *(const float4*)&Ysh[ee * 68 + rg * 8];
                const float4 yb = *(const float4*)&Ysh[ee * 68 + rg * 8 + 4];
                const float4 ma = *(const float4*)&Msh[ee * 260 + dg * 8];
                const float4 mb = *(const float4*)&Msh[ee * 260 + dg * 8 + 4];
                float ys[8] = {ya.x, ya.y, ya.z, ya.w, yb.x, yb.y, yb.z, yb.w};
                float ms[8] = {ma.x, ma.y, ma.z, ma.w, mb.x, mb.y, mb.z, mb.w};
                #pragma unroll
                for (int i = 0; i < 8; i++)
                    #pragma unroll
                    for (int j = 0; j < 8; j++)
                        acc[i][j] = fmaf(ys[i], ms[j], acc[i][j]);
            }
        }
        if (dg < 25) {
            #pragma unroll
            for (int i = 0; i < 8; i++) {
                int row = r0 + rg * 8 + i;
                if (row < R_CNT) {
                    *(float4*)&V[row * D_CNT + dg * 8]     = make_float4(acc[i][0], acc[i][1], acc[i][2], acc[i][3]);
                    *(float4*)&V[row * D_CNT + dg * 8 + 4] = make_float4(acc[i][4], acc[i][5], acc[i][6], acc[i][7]);
                }
            }
        }
    } else if (bid < 345) {
        // ---- uloss: one G-row ----
        float* Tsh = sh;                         // 6400 floats
        float* tn  = sh + 6400;                  // 32
        float4* red4 = (float4*)(sh + 6448);     // 16 floats, 16B-aligned
        for (int idx = tid; idx < 1600; idx += 256)
            ((float4*)Tsh)[idx] = ((const float4*)T_w)[idx];
        __syncthreads();
        int a = tid >> 3, k = tid & 7;
        float p = 0.f;
        #pragma unroll
        for (int j = 0; j < 25; ++j) { float t = Tsh[(k + 8*j)*32 + a]; p = fmaf(t, t, p); }
        p += __shfl_xor(p, 1); p += __shfl_xor(p, 2); p += __shfl_xor(p, 4);
        if (k == 0) tn[a] = fmaxf(sqrtf(p), 1e-12f);
        __syncthreads();
        const int i = bid - 313;
        float s = 0.f;
        #pragma unroll
        for (int j = 0; j < 25; ++j)
            s = fmaf(Tsh[(k + 8*j)*32 + i], Tsh[(k + 8*j)*32 + a], s);
        s += __shfl_xor(s, 1); s += __shfl_xor(s, 2); s += __shfl_xor(s, 4);
        float part = 0.f;
        if (k == 0) {
            float g = s / (tn[i] * tn[a]);
            float diff = g - ((i == a) ? 1.f : 0.f);
            part = diff * diff;
        }
        float4 tot = blk_reduce4(make_float4(part, 0.f, 0.f, 0.f), red4);
        if (tid == 0) upart[i] = tot.x;
    } else {
        // ---- init: zero UA/IA (262144 floats over 128 blocks) ----
        int base = (bid - 345) * 2048;
        #pragma unroll
        for (int j = 0; j < 8; ++j)
            out[OUT_UA + base + j * 256 + tid] = 0.f;
        if (bid == 345 && tid == 0) {
            dbl[0] = 0.0; dbl[1] = 0.0; dbl[2] = 0.0;
            int m = 1;
            for (int i = 1; i < 256; i += 2) if (u_idx[i] != 0) { m = 0; break; }
            *mode = m;
        }
    }
}

// ---- staging helpers: global_load_lds, uniform per-wave op counts ----
__device__ __forceinline__ void stage_E(const float* __restrict__ ew_src,
                                        float* ldsE, int w, int lane) {
    #pragma unroll
    for (int i = 0; i < 6; ++i) {
        int c = w * 6 + i;                 // chunk 0..23
        int f4 = c * 64 + lane;            // float4 index
        if (f4 > 1499) f4 = 1499;          // clamp tail into pad region
        __builtin_amdgcn_global_load_lds(
            (const __attribute__((address_space(1))) unsigned int*)(ew_src + (size_t)f4 * 4),
            (__attribute__((address_space(3))) unsigned int*)(ldsE + c * 256),
            16, 0, 0);
    }
}
__device__ __forceinline__ void stage_V(const float* __restrict__ v_src,
                                        float* ldsV, int w, int lane) {
    __builtin_amdgcn_global_load_lds(
        (const __attribute__((address_space(1))) unsigned int*)(v_src + w * 64 + lane),
        (__attribute__((address_space(3))) unsigned int*)(ldsV + w * 64),
        4, 0, 0);
}

// ---- K_attn: fused per-review pipeline, SINGLE-buffered LDS (26.8KB) ----
// 6 blocks/CU. Stage of review r+1 issued after B3 (bufE dead) into the same
// buffers; p_t+loss phases are the landing window; one full drain per review.
__global__ __launch_bounds__(256, 6) void k_attn(const float* __restrict__ e_w,
                                                 const float* __restrict__ V,
                                                 const float* __restrict__ z_n,
                                                 const float* __restrict__ W_w,
                                                 const float* __restrict__ W_b,
                                                 const float* __restrict__ T_w,
                                                 const float* __restrict__ T_b,
                                                 float* __restrict__ p_t,
                                                 float* __restrict__ out,
                                                 double* __restrict__ jpart) {
    __shared__ __align__(16) float bufE[6144];   // 24576 B (6000 used + pad)
    __shared__ __align__(16) float bufV[256];    // 1024 B
    __shared__ __align__(16) float zsh[D_CNT];   // 800 B
    __shared__ float axs[32], pts[32];
    __shared__ float4 red[8];
    const int tid = threadIdx.x;
    const int w = tid >> 6, lane = tid & 63;
    const float wb = W_b[tid >> 3];
    const float tb = (tid < D_CNT) ? T_b[tid] : 0.f;
    double jloc = 0.0;

    int r = blockIdx.x;
    stage_E(e_w + (size_t)r * 6000, bufE, w, lane);
    stage_V(V + (size_t)r * D_CNT, bufV, w, lane);
    __syncthreads();   // prologue full drain: buffers ready

    for (;;) {
        const int rn = r + KA_GRID;
        const bool have_next = (rn < R_CNT);

        // z_n rows for CURRENT review (regs; consumed in loss phase)
        float zn0 = 0.f, zn1 = 0.f;
        if (tid < D_CNT) {
            zn0 = z_n[(size_t)(2 * r) * D_CNT + tid];
            zn1 = z_n[(size_t)(2 * r + 1) * D_CNT + tid];
        }

        // dx[l] = e_w[l,:].v  (M_b.y_s bias constant over l -> cancels)
        if (tid < 240) {
            int l = tid >> 3, k = tid & 7;
            float p = 0.f;
            #pragma unroll
            for (int j = 0; j < 25; ++j)
                p = fmaf(bufE[l * 200 + k + 8 * j], bufV[k + 8 * j], p);
            p += __shfl_xor(p, 1); p += __shfl_xor(p, 2); p += __shfl_xor(p, 4);
            if (k == 0) axs[l] = p;
        }
        BAR_LDS();                               // B1 (bufV now dead)

        if (tid < 64) {                          // softmax over L=30
            float v = (tid < L_CNT) ? axs[tid] : -3.0e38f;
            float m = v;
            #pragma unroll
            for (int o = 32; o >= 1; o >>= 1) m = fmaxf(m, __shfl_xor(m, o));
            float e = (tid < L_CNT) ? __expf(v - m) : 0.f;
            float s = e;
            #pragma unroll
            for (int o = 32; o >= 1; o >>= 1) s += __shfl_xor(s, o);
            if (tid < L_CNT) axs[tid] = e / s;
        }
        BAR_LDS();                               // B2

        float zreg = 0.f;                        // z_s (register + LDS copy)
        if (tid < D_CNT) {
            #pragma unroll
            for (int l = 0; l < L_CNT; ++l)
                zreg = fmaf(bufE[l * 200 + tid], axs[l], zreg);
            zsh[tid] = zreg;
        }
        BAR_LDS();                               // B3 (bufE now dead)

        if (have_next) {                         // prefetch into freed buffers
            stage_E(e_w + (size_t)rn * 6000, bufE, w, lane);
            stage_V(V + (size_t)rn * D_CNT, bufV, w, lane);
        }

        {                                        // p_t (8 lanes per aspect)
            int a = tid >> 3, k = tid & 7;
            float p = 0.f;
            #pragma unroll
            for (int j = 0; j < 25; ++j)
                p = fmaf(zsh[k + 8 * j], W_w[a * 200 + k + 8 * j], p);
            p += __shfl_xor(p, 1); p += __shfl_xor(p, 2); p += __shfl_xor(p, 4);
            if (k == 0) {
                float pt = p + wb;
                pts[a] = pt;
                p_t[(size_t)r * 32 + a] = pt;
            }
        }
        BAR_LDS();                               // B4

        // r_s per-thread-d + fused 7-channel loss reduce
        float rv = 0.f;
        if (tid < D_CNT) {
            rv = tb;
            const float4* tw = (const float4*)(T_w + tid * 32);
            #pragma unroll
            for (int q = 0; q < 8; ++q) {
                float4 t = tw[q];
                rv = fmaf(t.x, pts[4 * q + 0], rv);
                rv = fmaf(t.y, pts[4 * q + 1], rv);
                rv = fmaf(t.z, pts[4 * q + 2], rv);
                rv = fmaf(t.w, pts[4 * q + 3], rv);
            }
        }
        float4 Av = make_float4(rv * rv, rv * zreg, zreg * zreg, zn0 * zn0);
        float4 Bv = make_float4(zn0 * rv, zn1 * zn1, zn1 * rv, 0.f);
        #pragma unroll
        for (int o = 32; o >= 1; o >>= 1) {
            Av.x += __shfl_xor(Av.x, o); Av.y += __shfl_xor(Av.y, o);
            Av.z += __shfl_xor(Av.z, o); Av.w += __shfl_xor(Av.w, o);
            Bv.x += __shfl_xor(Bv.x, o); Bv.y += __shfl_xor(Bv.y, o);
            Bv.z += __shfl_xor(Bv.z, o);
        }
        if ((tid & 63) == 0) { red[2 * w] = Av; red[2 * w + 1] = Bv; }

        BAR_FULL();                              // B5: staged data + stores landed

        if (tid == 0) {
            float rr = 0.f, rz = 0.f, zz = 0.f, n00 = 0.f, n0r = 0.f, n11 = 0.f, n1r = 0.f;
            #pragma unroll
            for (int i = 0; i < 4; ++i) {
                float4 a = red[2 * i], b = red[2 * i + 1];
                rr += a.x; rz += a.y; zz += a.z; n00 += a.w;
                n0r += b.x; n11 += b.y; n1r += b.z;
            }
            float nr = fmaxf(sqrtf(rr), 1e-12f);
            float nz = fmaxf(sqrtf(zz), 1e-12f);
            float c1  = rz  / (nr * nz);
            float c20 = n0r / (fmaxf(sqrtf(n00), 1e-12f) * nr);
            float c21 = n1r / (fmaxf(sqrtf(n11), 1e-12f) * nr);
            float l0 = fmaxf(0.f, 1.f - (c1 - c20));
            float l1 = fmaxf(0.f, 1.f - (c1 - c21));
            out[OUT_AB + 2 * r]     = l0;
            out[OUT_AB + 2 * r + 1] = l1;
            jloc += (double)l0 + (double)l1;
        }
        if (!have_next) break;
        r = rn;
    }
    if (tid == 0) jpart[blockIdx.x] = jloc;
}

// ---- K_scatter: user/item aspect segment sums via atomics ----
__global__ __launch_bounds__(256) void k_scatter(const int* __restrict__ u_idx,
                                                 const int* __restrict__ i_idx,
                                                 const float* __restrict__ u_val,
                                                 const float* __restrict__ i_val,
                                                 const float* __restrict__ p_t,
                                                 const int* __restrict__ mode,
                                                 float* __restrict__ out) {
    long long gid = (long long)blockIdx.x * 256 + threadIdx.x;
    const long long HALF = (long long)NNZ_CNT * 32;
    int is_item = gid >= HALF;
    long long rem = gid - (is_item ? HALF : 0);
    int k = (int)(rem >> 5), a = (int)(rem & 31);
    const int* idx = is_item ? i_idx : u_idx;
    const float* val = is_item ? i_val : u_val;
    int m64 = *mode;
    int row, col;
    if (m64) { row = idx[2 * k]; col = idx[2 * (NNZ_CNT + k)]; }
    else     { row = idx[k];     col = idx[NNZ_CNT + k]; }
    float v = p_t[col * 32 + a] * val[k];
    float* base = out + (is_item ? OUT_IA : OUT_UA);
    atomicAdd(&base[row * 32 + a], v);
}

// ---- K_fm: FM per-b terms; per-block partial of the global scalar S ----
__global__ __launch_bounds__(256) void k_fm(const float* __restrict__ out,
                                            const float* __restrict__ fc_w,
                                            const float* __restrict__ fc_b,
                                            const float* __restrict__ fm_V,
                                            float* __restrict__ fm_lin,
                                            double* __restrict__ spart) {
    __shared__ float parts[8];
    int tid = threadIdx.x;
    int a = tid & 31;
    int b = blockIdx.x * 8 + (tid >> 5);
    float ua = out[OUT_UA + b * 32 + a];
    float ia = out[OUT_IA + b * 32 + a];
    float oe = ua * ia;
    float oe2 = oe * oe;
    float lin = oe * fc_w[a];
    #pragma unroll
    for (int o = 1; o < 32; o <<= 1) lin += __shfl_xor(lin, o);
    float part = 0.f;
    #pragma unroll
    for (int j = 0; j < 10; j++) {
        float v = fm_V[a * 10 + j];
        float s1 = oe * v;
        float s2 = oe2 * v * v;
        #pragma unroll
        for (int o = 1; o < 32; o <<= 1) { s1 += __shfl_xor(s1, o); s2 += __shfl_xor(s2, o); }
        part += s1 * s1 - s2;
    }
    if (a == 0) {
        fm_lin[b] = lin + fc_b[0];
        parts[tid >> 5] = part;
    }
    __syncthreads();
    if (tid == 0) {
        float s = 0.f;
        #pragma unroll
        for (int i = 0; i < 8; ++i) s += parts[i];
        spart[blockIdx.x] = 0.5 * (double)s;
    }
}

// ---- K_predfinal: single block — S reduce, preds, rating loss, objective ----
__global__ __launch_bounds__(256) void k_predfinal(const float* __restrict__ label,
                                                   const float* __restrict__ fm_lin,
                                                   const double* __restrict__ spart,
                                                   const double* __restrict__ jpart,
                                                   const float* __restrict__ upart,
                                                   float* __restrict__ out) {
    __shared__ double dred[4];
    __shared__ float Ssh;
    int tid = threadIdx.x;
    // S = sum(spart[512])
    double sl = spart[tid] + spart[tid + 256];
    #pragma unroll
    for (int o = 32; o >= 1; o >>= 1) sl += __shfl_xor(sl, o);
    if ((tid & 63) == 0) dred[tid >> 6] = sl;
    __syncthreads();
    if (tid == 0) Ssh = (float)(dred[0] + dred[1] + dred[2] + dred[3]);
    __syncthreads();
    float S = Ssh;
    // predictions + rating losses
    double racc = 0.0;
    #pragma unroll
    for (int i = 0; i < 16; ++i) {
        int b = tid + 256 * i;
        float pred = fm_lin[b] + S + AVG_RATING;
        float d = pred - label[b];
        float rl = d * d;
        out[OUT_PRED + b] = pred;
        out[OUT_RL + b] = rl;
        racc += (double)rl;
    }
    // J partials and U partials
    double jacc = 0.0;
    for (int i = tid; i < KA_GRID; i += 256) jacc += jpart[i];
    float u = (tid < 32) ? upart[tid] : 0.f;
    #pragma unroll
    for (int o = 32; o >= 1; o >>= 1) {
        racc += __shfl_xor(racc, o);
        jacc += __shfl_xor(jacc, o);
        u    += __shfl_xor(u, o);
    }
    __syncthreads();
    if ((tid & 63) == 0) dred[tid >> 6] = racc;
    __syncthreads();
    double rsum = dred[0] + dred[1] + dred[2] + dred[3];
    __syncthreads();
    if ((tid & 63) == 0) dred[tid >> 6] = jacc;
    __syncthreads();
    double jsum = dred[0] + dred[1] + dred[2] + dred[3];
    __shared__ float ured[4];
    if ((tid & 63) == 0) ured[tid >> 6] = u;
    __syncthreads();
    if (tid == 0) {
        double U = (double)(ured[0] + ured[1] + ured[2] + ured[3]) / 1024.0;
        double J = jsum / (2.0 * R_CNT);
        double RL = rsum / (double)B_CNT;
        out[OUT_OBJ] = (float)(RL + U + J);
    }
}

extern "C" void kernel_launch(void* const* d_in, const int* in_sizes, int n_in,
                              void* d_out, int out_size, void* d_ws, size_t ws_size,
                              hipStream_t stream) {
    const float* e_w   = (const float*)d_in[0];
    const float* y_s   = (const float*)d_in[1];
    const float* z_n   = (const float*)d_in[2];
    const float* label = (const float*)d_in[3];
    const float* u_val = (const float*)d_in[4];
    const float* i_val = (const float*)d_in[5];
    const float* M_w   = (const float*)d_in[6];
    const float* W_w   = (const float*)d_in[8];
    const float* W_b   = (const float*)d_in[9];
    const float* T_w   = (const float*)d_in[10];
    const float* T_b   = (const float*)d_in[11];
    const float* fc_w  = (const float*)d_in[12];
    const float* fc_b  = (const float*)d_in[13];
    const float* fm_V  = (const float*)d_in[14];
    const int*   u_idx = (const int*)d_in[15];
    const int*   i_idx = (const int*)d_in[16];

    float* out = (float*)d_out;
    char* ws = (char*)d_ws;
    double* dbl   = (double*)(ws + WS_DBL);
    int* mode     = (int*)(ws + WS_MODE);
    float* fm_lin = (float*)(ws + WS_FMLIN);
    float* p_t    = (float*)(ws + WS_PT);
    float* V      = (float*)(ws + WS_V);
    double* jpart = (double*)(ws + WS_JPART);
    double* spart = (double*)(ws + WS_SPART);
    float* upart  = (float*)(ws + WS_UPART);

    k_pre<<<473, 256, 0, stream>>>(y_s, M_w, T_w, u_idx, V, upart, out, dbl, mode);
    k_attn<<<KA_GRID, 256, 0, stream>>>(e_w, V, z_n, W_w, W_b, T_w, T_b,
                                        p_t, out, jpart);
    k_scatter<<<(2 * NNZ_CNT * 32) / 256, 256, 0, stream>>>(u_idx, i_idx, u_val, i_val,
                                                            p_t, mode, out);
    k_fm<<<B_CNT / 8, 256, 0, stream>>>(out, fc_w, fc_b, fm_V, fm_lin, spart);
    k_predfinal<<<1, 256, 0, stream>>>(label, fm_lin, spart, jpart, upart, out);
}